// Round 2
// baseline (126.647 us; speedup 1.0000x reference)
//
#include <hip/hip_runtime.h>
#include <math.h>

// Hit-miss transform: out[i][j] = min_{di,dj}(x[i+di][j+dj] - Khit[di][dj])
//                               - max_{di,dj}(x[i+di][j+dj] - Kmiss[di][dj])
// H=W=4096 fp32 input, 5x5 kernels, output 4092x4092 fp32.
//
// R5: accumulator-transposed streaming. R4's counters showed VGPR_Count=32 —
// the compiler REFUSED the 6x8 register row window (needs 48+ regs) and
// rematerialized loads instead: ~10 dwordx4 + addressing per output row,
// inflating VALU to ~142 instrs/pixel (vs ~79 core). Fix: invert the nest —
// stream each input row ONCE; it updates the accumulators of the <=4 output
// rows whose window contains it, then dies. Accumulators (mn/mx[4][4] = 32
// VGPRs) carry the loop dependency and cannot be rematerialized, forcing
// register residency. Loads: 16 dwordx4 per 4-row strip (was ~40).
// Grid packing kept: 4 x 1023 = 4092 blocks = 2 exact resident rounds.

constexpr int KS  = 5;
constexpr int WW  = 4096;
constexpr int HO  = 4092;
constexpr int WO  = 4092;
constexpr int CG  = WO / 4;   // 1023 column groups
constexpr int RPT = 4;        // output rows per thread (4092 = 4*1023)

__device__ __forceinline__ float min3f(float a, float b, float c) {
    float d;
    asm("v_min3_f32 %0, %1, %2, %3" : "=v"(d) : "v"(a), "v"(b), "v"(c));
    return d;
}
__device__ __forceinline__ float max3f(float a, float b, float c) {
    float d;
    asm("v_max3_f32 %0, %1, %2, %3" : "=v"(d) : "v"(a), "v"(b), "v"(c));
    return d;
}

__global__ __launch_bounds__(256) void hitmiss_kernel(
    const float* __restrict__ x,
    const float* __restrict__ kh,
    const float* __restrict__ km,
    float* __restrict__ out)
{
    const int cg = blockIdx.x * blockDim.x + threadIdx.x;  // column group
    if (cg >= CG) return;
    const int j0 = cg * 4;
    const int r0 = blockIdx.y * RPT;

    // Kernel weights: uniform addresses -> scalar (SGPR) loads.
    float wh[KS * KS], wm[KS * KS];
#pragma unroll
    for (int i = 0; i < KS * KS; ++i) {
        wh[i] = kh[i];
        wm[i] = km[i];
    }

    const float* base = x + (size_t)r0 * WW + j0;

    // Accumulators for RPT output rows x 4 pixels. These carry the loop
    // dependency -> must stay register-resident.
    float mn[RPT][4], mx[RPT][4];

#pragma unroll
    for (int i = 0; i < RPT + 4; ++i) {
        // Load input row r0+i exactly once (2x dwordx4), consume, discard.
        float4 a = *reinterpret_cast<const float4*>(base + (size_t)i * WW);
        float4 b = *reinterpret_cast<const float4*>(base + (size_t)i * WW + 4);
        const float v[8] = {a.x, a.y, a.z, a.w, b.x, b.y, b.z, b.w};

#pragma unroll
        for (int o = 0; o < RPT; ++o) {
            const int di = i - o;              // static after unroll
            if (di < 0 || di > KS - 1) continue;
#pragma unroll
            for (int p = 0; p < 4; ++p) {
                // hit side: min over the 5 columns of kernel row di
                const float t0 = v[p + 0] - wh[di * KS + 0];
                const float t1 = v[p + 1] - wh[di * KS + 1];
                const float t2 = v[p + 2] - wh[di * KS + 2];
                const float t3 = v[p + 3] - wh[di * KS + 3];
                const float t4 = v[p + 4] - wh[di * KS + 4];
                const float m5 = min3f(t3, t4, min3f(t0, t1, t2));
                mn[o][p] = (di == 0) ? m5 : fminf(mn[o][p], m5);

                // miss side: max over the 5 columns of kernel row di
                const float u0 = v[p + 0] - wm[di * KS + 0];
                const float u1 = v[p + 1] - wm[di * KS + 1];
                const float u2 = v[p + 2] - wm[di * KS + 2];
                const float u3 = v[p + 3] - wm[di * KS + 3];
                const float u4 = v[p + 4] - wm[di * KS + 4];
                const float x5 = max3f(u3, u4, max3f(u0, u1, u2));
                mx[o][p] = (di == 0) ? x5 : fmaxf(mx[o][p], x5);
            }
        }

        // Output row o = i-4 got its last contribution this iteration;
        // store now and free its accumulators.
        if (i >= KS - 1) {
            const int o = i - (KS - 1);
            float4 oo;
            oo.x = mn[o][0] - mx[o][0];
            oo.y = mn[o][1] - mx[o][1];
            oo.z = mn[o][2] - mx[o][2];
            oo.w = mn[o][3] - mx[o][3];
            *reinterpret_cast<float4*>(out + (size_t)(r0 + o) * WO + j0) = oo;
        }
    }
}

extern "C" void kernel_launch(void* const* d_in, const int* in_sizes, int n_in,
                              void* d_out, int out_size, void* d_ws, size_t ws_size,
                              hipStream_t stream) {
    const float* x  = (const float*)d_in[0];
    const float* kh = (const float*)d_in[1];
    const float* km = (const float*)d_in[2];
    float* out = (float*)d_out;

    dim3 block(256, 1, 1);
    dim3 grid((CG + 255) / 256, HO / RPT, 1);  // 4 x 1023 = 4092 blocks ~= 2 x 2048 resident
    hipLaunchKernelGGL(hitmiss_kernel, grid, block, 0, stream, x, kh, km, out);
}